// Round 11
// baseline (68.598 us; speedup 1.0000x reference)
//
#include <hip/hip_runtime.h>
#include <hip/hip_bf16.h>

#define N_NODES 100000
#define D 64
#define BSHIFT 6
#define BNODES 64         // nodes per bucket
#define NB 1563           // ceil(100000/64)
#define CHUNK 8192
#define LDS_CAP 1024      // edges per bucket in LDS (mean ~800, sd ~28)

typedef __attribute__((ext_vector_type(4))) _Float16 half4;

// ---------- K1: feature f32->f16 conversion + per-(chunk,bucket) histogram ----------
__global__ void convhist(const float4* __restrict__ feat4, half4* __restrict__ feat16,
                         int n4, const int* __restrict__ dst, int* __restrict__ counts,
                         int nchunk, int n_edges) {
    for (int i = blockIdx.x * blockDim.x + threadIdx.x; i < n4;
         i += gridDim.x * blockDim.x) {
        float4 v = feat4[i];
        half4 h;
        h.x = (_Float16)v.x; h.y = (_Float16)v.y;
        h.z = (_Float16)v.z; h.w = (_Float16)v.w;
        feat16[i] = h;
    }
    __shared__ int h[NB];
    int c = blockIdx.x;
    if (c >= nchunk) return;
    for (int i = threadIdx.x; i < NB; i += blockDim.x) h[i] = 0;
    __syncthreads();
    int s = c * CHUNK, e = min(s + CHUNK, n_edges);
    for (int i = s + threadIdx.x; i < e; i += blockDim.x)
        atomicAdd(&h[dst[i] >> BSHIFT], 1);
    __syncthreads();
    for (int b = threadIdx.x; b < NB; b += blockDim.x)
        counts[(size_t)b * nchunk + c] = h[b];   // bucket-major
}

// ---------- K2: per-bucket exclusive scan over chunk counts ----------
__global__ void scanB(int* __restrict__ counts, int* __restrict__ totals, int nchunk) {
    __shared__ int s[256];
    int b = blockIdx.x;
    int tid = threadIdx.x;
    int carry = 0;
    int* row = counts + (size_t)b * nchunk;
    for (int t0 = 0; t0 < nchunk; t0 += 256) {
        int i = t0 + tid;
        int v = (i < nchunk) ? row[i] : 0;
        s[tid] = v;
        __syncthreads();
        for (int off = 1; off < 256; off <<= 1) {
            int t = (tid >= off) ? s[tid - off] : 0;
            __syncthreads();
            s[tid] += t;
            __syncthreads();
        }
        if (i < nchunk) row[i] = s[tid] - v + carry;
        carry += s[255];
        __syncthreads();
    }
    if (tid == 0) totals[b] = carry;
}

// ---------- K2b: exclusive scan of totals (NB may exceed block size: carry loop) ----------
__global__ void baseK(const int* __restrict__ totals, int* __restrict__ base,
                      int n_edges) {
    __shared__ int s[1024];
    int tid = threadIdx.x;
    int carry = 0;
    for (int t0 = 0; t0 < NB; t0 += 1024) {
        int i = t0 + tid;
        int v = (i < NB) ? totals[i] : 0;
        s[tid] = v;
        __syncthreads();
        for (int off = 1; off < 1024; off <<= 1) {
            int t = (tid >= off) ? s[tid - off] : 0;
            __syncthreads();
            s[tid] += t;
            __syncthreads();
        }
        if (i < NB) base[i] = s[tid] - v + carry;
        carry += s[1023];
        __syncthreads();
    }
    if (tid == 0) base[NB] = n_edges;
}

// ---------- K3: scatter to bucket order ----------
__global__ void scatter2(const int* __restrict__ src, const int* __restrict__ dst,
                         const int* __restrict__ counts, const int* __restrict__ base,
                         unsigned* __restrict__ sorted, int nchunk, int n_edges) {
    __shared__ int cur[NB];
    int tid = threadIdx.x;      // 1024
    int c = blockIdx.x;
    for (int b = tid; b < NB; b += blockDim.x)
        cur[b] = base[b] + counts[(size_t)b * nchunk + c];
    __syncthreads();
    int s = c * CHUNK, e = min(s + CHUNK, n_edges);
    for (int i = s + tid; i < e; i += blockDim.x) {
        int d = dst[i];
        int b = d >> BSHIFT;
        int r = atomicAdd(&cur[b], 1);
        sorted[r] = ((unsigned)(d & (BNODES - 1)) << 17) | (unsigned)src[i];
    }
}

// ---------- K4: per-bucket counting sort into LDS + flat-stream fp16 gather ----------
__global__ void sortGather(const _Float16* __restrict__ feat16,
                           const unsigned* __restrict__ sorted,
                           const int* __restrict__ base,
                           unsigned* __restrict__ sorted2,   // spill path only
                           float* __restrict__ out) {
    __shared__ int cnt[BNODES];
    __shared__ int scn[BNODES];
    __shared__ int noff[BNODES + 1];
    __shared__ int cur[BNODES];
    __shared__ unsigned lsrc[LDS_CAP];
    int tid = threadIdx.x;      // 256
    int b = blockIdx.x;

    int start = base[b];
    int cntb = base[b + 1] - start;
    bool big = (cntb > LDS_CAP);

    // stage up to 4 edges/thread in registers (single global read of sorted)
    unsigned p0 = 0, p1 = 0, p2 = 0, p3 = 0;
    int i0 = tid, i1 = tid + 256, i2 = tid + 512, i3 = tid + 768;
    if (!big) {
        if (i0 < cntb) p0 = sorted[start + i0];
        if (i1 < cntb) p1 = sorted[start + i1];
        if (i2 < cntb) p2 = sorted[start + i2];
        if (i3 < cntb) p3 = sorted[start + i3];
    }

    if (tid < BNODES) cnt[tid] = 0;
    __syncthreads();
    if (!big) {
        if (i0 < cntb) atomicAdd(&cnt[(p0 >> 17) & (BNODES - 1)], 1);
        if (i1 < cntb) atomicAdd(&cnt[(p1 >> 17) & (BNODES - 1)], 1);
        if (i2 < cntb) atomicAdd(&cnt[(p2 >> 17) & (BNODES - 1)], 1);
        if (i3 < cntb) atomicAdd(&cnt[(p3 >> 17) & (BNODES - 1)], 1);
    } else {
        for (int i = tid; i < cntb; i += 256)
            atomicAdd(&cnt[(sorted[start + i] >> 17) & (BNODES - 1)], 1);
    }
    __syncthreads();

    // scan BNODES counts
    int v = (tid < BNODES) ? cnt[tid] : 0;
    if (tid < BNODES) scn[tid] = v;
    __syncthreads();
    for (int off = 1; off < BNODES; off <<= 1) {
        int t = 0;
        if (tid < BNODES && tid >= off) t = scn[tid - off];
        __syncthreads();
        if (tid < BNODES) scn[tid] += t;
        __syncthreads();
    }
    if (tid < BNODES) { noff[tid] = scn[tid] - v; cur[tid] = scn[tid] - v; }
    if (tid == 0) noff[BNODES] = cntb;
    __syncthreads();

    // place (src only; order within a node irrelevant for a sum)
    if (!big) {
        if (i0 < cntb) { int q = atomicAdd(&cur[(p0 >> 17) & (BNODES - 1)], 1); lsrc[q] = p0 & 0x1FFFF; }
        if (i1 < cntb) { int q = atomicAdd(&cur[(p1 >> 17) & (BNODES - 1)], 1); lsrc[q] = p1 & 0x1FFFF; }
        if (i2 < cntb) { int q = atomicAdd(&cur[(p2 >> 17) & (BNODES - 1)], 1); lsrc[q] = p2 & 0x1FFFF; }
        if (i3 < cntb) { int q = atomicAdd(&cur[(p3 >> 17) & (BNODES - 1)], 1); lsrc[q] = p3 & 0x1FFFF; }
    } else {
        for (int i = tid; i < cntb; i += 256) {
            unsigned p = sorted[start + i];
            int q = atomicAdd(&cur[(p >> 17) & (BNODES - 1)], 1);
            sorted2[start + q] = p & 0x1FFFF;
        }
    }
    __syncthreads();

    // gather: 16 groups of 16 lanes; each group streams its 4 nodes' union range
    int g = tid >> 4, gl = tid & 15;
    int n0 = g * 4;
    int nodeBase = b << BSHIFT;

    if (!big) {
        int eEnd = noff[n0 + 4];
        int n = n0;
        int nend = noff[n + 1];
        float4 acc = make_float4(0.f, 0.f, 0.f, 0.f);

#define FIN                                                                   \
        {                                                                     \
            int dg = nend - noff[n];                                          \
            float inv = (dg > 0) ? 1.0f / (float)dg : 0.0f;                   \
            int node = nodeBase + n;                                          \
            if (node < N_NODES) {                                             \
                float4 o = make_float4(acc.x * inv, acc.y * inv,              \
                                       acc.z * inv, acc.w * inv);             \
                *reinterpret_cast<float4*>(&out[(size_t)node * D + gl * 4]) = o; \
            }                                                                 \
            acc = make_float4(0.f, 0.f, 0.f, 0.f);                            \
            n++;                                                              \
            nend = (n < BNODES) ? noff[n + 1] : 0x7fffffff;                   \
        }

        for (int ebase = noff[n0]; ebase < eEnd; ebase += 8) {
            int m = eEnd - ebase; if (m > 8) m = 8;
#define LDV(k)                                                                \
            half4 v##k;                                                       \
            if (k < m) {                                                      \
                int s = (int)(lsrc[ebase + k] & 0x1FFFF);                     \
                v##k = *reinterpret_cast<const half4*>(                       \
                    &feat16[(size_t)s * D + gl * 4]);                         \
            }
            LDV(0) LDV(1) LDV(2) LDV(3) LDV(4) LDV(5) LDV(6) LDV(7)
#undef LDV
#define ACCK(k)                                                               \
            if (k < m) {                                                      \
                int ee = ebase + k;                                           \
                while (ee == nend) FIN;                                       \
                acc.x += (float)v##k.x; acc.y += (float)v##k.y;               \
                acc.z += (float)v##k.z; acc.w += (float)v##k.w;               \
            }
            ACCK(0) ACCK(1) ACCK(2) ACCK(3) ACCK(4) ACCK(5) ACCK(6) ACCK(7)
#undef ACCK
        }
        while (n < n0 + 4) FIN;
#undef FIN
    } else {
        // rare spill path: simple per-node loop from global sorted2
        for (int n = n0; n < n0 + 4; n++) {
            int node = nodeBase + n;
            if (node >= N_NODES) break;
            int off = noff[n], endn = noff[n + 1];
            int deg = endn - off;
            float4 acc = make_float4(0.f, 0.f, 0.f, 0.f);
            for (int e = off; e < endn; e++) {
                int s = (int)sorted2[start + e];
                half4 vv = *reinterpret_cast<const half4*>(&feat16[(size_t)s * D + gl * 4]);
                acc.x += (float)vv.x; acc.y += (float)vv.y;
                acc.z += (float)vv.z; acc.w += (float)vv.w;
            }
            float inv = (deg > 0) ? 1.0f / (float)deg : 0.0f;
            float4 o = make_float4(acc.x * inv, acc.y * inv, acc.z * inv, acc.w * inv);
            *reinterpret_cast<float4*>(&out[(size_t)node * D + gl * 4]) = o;
        }
    }
}

// ---------- fallback (atomic scatter) if ws too small ----------
__global__ void gcn_scatter(const float* __restrict__ feat, const int* __restrict__ src,
                            const int* __restrict__ dst, float* __restrict__ out,
                            float* __restrict__ deg, int n_edges) {
    long long gtid = (long long)blockIdx.x * blockDim.x + threadIdx.x;
    int edge = (int)(gtid >> 6);
    int lane = threadIdx.x & 63;
    if (edge >= n_edges) return;
    atomicAdd(&out[(long long)dst[edge] * D + lane],
              feat[(long long)src[edge] * D + lane]);
    if (lane == 0) atomicAdd(&deg[dst[edge]], 1.0f);
}
__global__ void gcn_finalize(float* __restrict__ out, const float* __restrict__ deg,
                             int total) {
    int i = blockIdx.x * blockDim.x + threadIdx.x;
    if (i >= total) return;
    float dg = deg[i >> 6];
    out[i] = (dg > 0.0f) ? out[i] / dg : 0.0f;
}

extern "C" void kernel_launch(void* const* d_in, const int* in_sizes, int n_in,
                              void* d_out, int out_size, void* d_ws, size_t ws_size,
                              hipStream_t stream) {
    const float* feat = (const float*)d_in[0];
    const int* src = (const int*)d_in[1];
    const int* dst = (const int*)d_in[2];
    float* out = (float*)d_out;
    int n_edges = in_sizes[1];

    int nchunk = (n_edges + CHUNK - 1) / CHUNK;
    size_t ncounts = (size_t)NB * nchunk;
    size_t f16_bytes = (size_t)N_NODES * D * sizeof(_Float16);   // 12.8 MB
    size_t need = f16_bytes + (ncounts + NB + NB + 1) * sizeof(int)
                + (size_t)n_edges * 2 * sizeof(unsigned);

    if (ws_size < need) {
        float* deg = (float*)d_ws;
        int total = N_NODES * D;
        hipMemsetAsync(out, 0, (size_t)total * sizeof(float), stream);
        hipMemsetAsync(deg, 0, (size_t)N_NODES * sizeof(float), stream);
        long long threads = (long long)n_edges * 64;
        int grid = (int)((threads + 255) / 256);
        gcn_scatter<<<grid, 256, 0, stream>>>(feat, src, dst, out, deg, n_edges);
        gcn_finalize<<<(total + 255) / 256, 256, 0, stream>>>(out, deg, total);
        return;
    }

    char* wp = (char*)d_ws;
    _Float16* feat16 = (_Float16*)wp;            wp += f16_bytes;
    int* counts = (int*)wp;                      wp += ncounts * sizeof(int);
    int* totals = (int*)wp;                      wp += (size_t)NB * sizeof(int);
    int* base = (int*)wp;                        wp += (size_t)(NB + 1) * sizeof(int);
    unsigned* sorted = (unsigned*)wp;            wp += (size_t)n_edges * sizeof(unsigned);
    unsigned* sorted2 = (unsigned*)wp;           // spill path only

    int n4 = N_NODES * D / 4;
    int chgrid = (nchunk > 256) ? nchunk : 256;
    convhist<<<chgrid, 1024, 0, stream>>>((const float4*)feat, (half4*)feat16, n4,
                                          dst, counts, nchunk, n_edges);
    scanB<<<NB, 256, 0, stream>>>(counts, totals, nchunk);
    baseK<<<1, 1024, 0, stream>>>(totals, base, n_edges);
    scatter2<<<nchunk, 1024, 0, stream>>>(src, dst, counts, base, sorted,
                                          nchunk, n_edges);
    sortGather<<<NB, 256, 0, stream>>>(feat16, sorted, base, sorted2, out);
}

// Round 12
// 58.889 us; speedup vs baseline: 1.1649x; 1.1649x over previous
//
#include <hip/hip_runtime.h>
#include <hip/hip_bf16.h>

#define N_NODES 100000
#define D 64
#define BSHIFT 8
#define BNODES 256        // nodes per bucket
#define NB 391            // ceil(100000/256)
#define CHUNK 8192
#define LDS_CAP 4096      // edges per bucket in LDS (mean 3200, sd ~56)

typedef __attribute__((ext_vector_type(8))) _Float16 half8;

// ---------- K1: feature f32->f16 conversion + per-(chunk,bucket) histogram ----------
__global__ void convhist(const float4* __restrict__ feat4, float4* __restrict__ feat16,
                         int n4pairs, const int* __restrict__ dst, int* __restrict__ counts,
                         int nchunk, int n_edges) {
    // conv: process 8 floats (2×float4 in, 1×half8=float4-sized out) per iter
    for (int i = blockIdx.x * blockDim.x + threadIdx.x; i < n4pairs;
         i += gridDim.x * blockDim.x) {
        float4 a = feat4[i * 2];
        float4 b = feat4[i * 2 + 1];
        half8 h;
        h[0] = (_Float16)a.x; h[1] = (_Float16)a.y;
        h[2] = (_Float16)a.z; h[3] = (_Float16)a.w;
        h[4] = (_Float16)b.x; h[5] = (_Float16)b.y;
        h[6] = (_Float16)b.z; h[7] = (_Float16)b.w;
        *reinterpret_cast<half8*>(&feat16[i]) = h;
    }
    __shared__ int h[NB];
    int c = blockIdx.x;
    if (c >= nchunk) return;
    for (int i = threadIdx.x; i < NB; i += blockDim.x) h[i] = 0;
    __syncthreads();
    int s = c * CHUNK, e = min(s + CHUNK, n_edges);
    for (int i = s + threadIdx.x; i < e; i += blockDim.x)
        atomicAdd(&h[dst[i] >> BSHIFT], 1);
    __syncthreads();
    for (int b = threadIdx.x; b < NB; b += blockDim.x)
        counts[(size_t)b * nchunk + c] = h[b];   // bucket-major
}

// ---------- K2: per-bucket exclusive scan over chunk counts ----------
__global__ void scanB(int* __restrict__ counts, int* __restrict__ totals, int nchunk) {
    __shared__ int s[256];
    int b = blockIdx.x;
    int tid = threadIdx.x;
    int carry = 0;
    int* row = counts + (size_t)b * nchunk;
    for (int t0 = 0; t0 < nchunk; t0 += 256) {
        int i = t0 + tid;
        int v = (i < nchunk) ? row[i] : 0;
        s[tid] = v;
        __syncthreads();
        for (int off = 1; off < 256; off <<= 1) {
            int t = (tid >= off) ? s[tid - off] : 0;
            __syncthreads();
            s[tid] += t;
            __syncthreads();
        }
        if (i < nchunk) row[i] = s[tid] - v + carry;
        carry += s[255];
        __syncthreads();
    }
    if (tid == 0) totals[b] = carry;
}

// ---------- K2b: exclusive scan of totals -> bucket base (one block, NB<=1024) ----------
__global__ void baseK(const int* __restrict__ totals, int* __restrict__ base,
                      int n_edges) {
    __shared__ int s[1024];
    int tid = threadIdx.x;
    int v = (tid < NB) ? totals[tid] : 0;
    s[tid] = v;
    __syncthreads();
    for (int off = 1; off < 1024; off <<= 1) {
        int t = (tid >= off) ? s[tid - off] : 0;
        __syncthreads();
        s[tid] += t;
        __syncthreads();
    }
    if (tid < NB) base[tid] = s[tid] - v;
    if (tid == 0) base[NB] = n_edges;
}

// ---------- K3: scatter to bucket order ----------
__global__ void scatter2(const int* __restrict__ src, const int* __restrict__ dst,
                         const int* __restrict__ counts, const int* __restrict__ base,
                         unsigned* __restrict__ sorted, int nchunk, int n_edges) {
    __shared__ int cur[NB];
    int tid = threadIdx.x;      // 1024
    int c = blockIdx.x;
    for (int b = tid; b < NB; b += blockDim.x)
        cur[b] = base[b] + counts[(size_t)b * nchunk + c];
    __syncthreads();
    int s = c * CHUNK, e = min(s + CHUNK, n_edges);
    for (int i = s + tid; i < e; i += blockDim.x) {
        int d = dst[i];
        int b = d >> BSHIFT;
        int r = atomicAdd(&cur[b], 1);
        sorted[r] = ((unsigned)(d & (BNODES - 1)) << 17) | (unsigned)src[i];
    }
}

// ---------- K4: per-bucket counting sort into LDS + fp16 gather (8-lane x half8) ----------
__global__ void sortGather(const _Float16* __restrict__ feat16,
                           const unsigned* __restrict__ sorted,
                           const int* __restrict__ base,
                           unsigned* __restrict__ sorted2,   // spill path only
                           float* __restrict__ out) {
    __shared__ int cnt[BNODES];
    __shared__ int scn[BNODES];
    __shared__ int noff[BNODES + 1];
    __shared__ int cur[BNODES];
    __shared__ unsigned lsrc[LDS_CAP];
    int tid = threadIdx.x;      // 1024
    int b = blockIdx.x;

    int start = base[b];
    int cntb = base[b + 1] - start;
    bool big = (cntb > LDS_CAP);

    // stage up to 4 edges/thread in registers (single global read of sorted)
    unsigned p0 = 0, p1 = 0, p2 = 0, p3 = 0;
    int i0 = tid, i1 = tid + 1024, i2 = tid + 2048, i3 = tid + 3072;
    if (!big) {
        if (i0 < cntb) p0 = sorted[start + i0];
        if (i1 < cntb) p1 = sorted[start + i1];
        if (i2 < cntb) p2 = sorted[start + i2];
        if (i3 < cntb) p3 = sorted[start + i3];
    }

    if (tid < BNODES) cnt[tid] = 0;
    __syncthreads();
    if (!big) {
        if (i0 < cntb) atomicAdd(&cnt[(p0 >> 17) & (BNODES - 1)], 1);
        if (i1 < cntb) atomicAdd(&cnt[(p1 >> 17) & (BNODES - 1)], 1);
        if (i2 < cntb) atomicAdd(&cnt[(p2 >> 17) & (BNODES - 1)], 1);
        if (i3 < cntb) atomicAdd(&cnt[(p3 >> 17) & (BNODES - 1)], 1);
    } else {
        for (int i = tid; i < cntb; i += 1024)
            atomicAdd(&cnt[(sorted[start + i] >> 17) & (BNODES - 1)], 1);
    }
    __syncthreads();

    // scan BNODES counts
    int v = (tid < BNODES) ? cnt[tid] : 0;
    if (tid < BNODES) scn[tid] = v;
    __syncthreads();
    for (int off = 1; off < BNODES; off <<= 1) {
        int t = 0;
        if (tid < BNODES && tid >= off) t = scn[tid - off];
        __syncthreads();
        if (tid < BNODES) scn[tid] += t;
        __syncthreads();
    }
    if (tid < BNODES) { noff[tid] = scn[tid] - v; cur[tid] = scn[tid] - v; }
    if (tid == 0) noff[BNODES] = cntb;
    __syncthreads();

    // place (src only; order within node irrelevant for a sum)
    if (!big) {
        if (i0 < cntb) { int q = atomicAdd(&cur[(p0 >> 17) & (BNODES - 1)], 1); lsrc[q] = p0 & 0x1FFFF; }
        if (i1 < cntb) { int q = atomicAdd(&cur[(p1 >> 17) & (BNODES - 1)], 1); lsrc[q] = p1 & 0x1FFFF; }
        if (i2 < cntb) { int q = atomicAdd(&cur[(p2 >> 17) & (BNODES - 1)], 1); lsrc[q] = p2 & 0x1FFFF; }
        if (i3 < cntb) { int q = atomicAdd(&cur[(p3 >> 17) & (BNODES - 1)], 1); lsrc[q] = p3 & 0x1FFFF; }
    } else {
        for (int i = tid; i < cntb; i += 1024) {
            unsigned p = sorted[start + i];
            int q = atomicAdd(&cur[(p >> 17) & (BNODES - 1)], 1);
            sorted2[start + q] = p & 0x1FFFF;
        }
    }
    __syncthreads();

    // gather: 128 groups of 8 lanes; lane covers 8 fp16 (16B load); 2 nodes per group
    int g = tid >> 3, gl = tid & 7;
    for (int n = g; n < BNODES; n += 128) {
        int node = (b << BSHIFT) + n;
        if (node >= N_NODES) break;
        int off = noff[n], endn = noff[n + 1];
        int deg = endn - off;
        float4 accA = make_float4(0.f, 0.f, 0.f, 0.f);
        float4 accB = make_float4(0.f, 0.f, 0.f, 0.f);
        int e = off;
        if (!big) {
            for (; e + 4 <= endn; e += 4) {
                int s0 = lsrc[e], s1 = lsrc[e + 1], s2 = lsrc[e + 2], s3 = lsrc[e + 3];
                half8 v0 = *reinterpret_cast<const half8*>(&feat16[(size_t)s0 * D + gl * 8]);
                half8 v1 = *reinterpret_cast<const half8*>(&feat16[(size_t)s1 * D + gl * 8]);
                half8 v2 = *reinterpret_cast<const half8*>(&feat16[(size_t)s2 * D + gl * 8]);
                half8 v3 = *reinterpret_cast<const half8*>(&feat16[(size_t)s3 * D + gl * 8]);
                accA.x += (float)v0[0] + (float)v1[0] + (float)v2[0] + (float)v3[0];
                accA.y += (float)v0[1] + (float)v1[1] + (float)v2[1] + (float)v3[1];
                accA.z += (float)v0[2] + (float)v1[2] + (float)v2[2] + (float)v3[2];
                accA.w += (float)v0[3] + (float)v1[3] + (float)v2[3] + (float)v3[3];
                accB.x += (float)v0[4] + (float)v1[4] + (float)v2[4] + (float)v3[4];
                accB.y += (float)v0[5] + (float)v1[5] + (float)v2[5] + (float)v3[5];
                accB.z += (float)v0[6] + (float)v1[6] + (float)v2[6] + (float)v3[6];
                accB.w += (float)v0[7] + (float)v1[7] + (float)v2[7] + (float)v3[7];
            }
            for (; e < endn; e++) {
                int s = lsrc[e];
                half8 vv = *reinterpret_cast<const half8*>(&feat16[(size_t)s * D + gl * 8]);
                accA.x += (float)vv[0]; accA.y += (float)vv[1];
                accA.z += (float)vv[2]; accA.w += (float)vv[3];
                accB.x += (float)vv[4]; accB.y += (float)vv[5];
                accB.z += (float)vv[6]; accB.w += (float)vv[7];
            }
        } else {
            for (; e < endn; e++) {
                int s = (int)sorted2[start + e];
                half8 vv = *reinterpret_cast<const half8*>(&feat16[(size_t)s * D + gl * 8]);
                accA.x += (float)vv[0]; accA.y += (float)vv[1];
                accA.z += (float)vv[2]; accA.w += (float)vv[3];
                accB.x += (float)vv[4]; accB.y += (float)vv[5];
                accB.z += (float)vv[6]; accB.w += (float)vv[7];
            }
        }
        float inv = (deg > 0) ? 1.0f / (float)deg : 0.0f;
        float4 oA = make_float4(accA.x * inv, accA.y * inv, accA.z * inv, accA.w * inv);
        float4 oB = make_float4(accB.x * inv, accB.y * inv, accB.z * inv, accB.w * inv);
        float* orow = &out[(size_t)node * D + gl * 8];
        *reinterpret_cast<float4*>(orow) = oA;
        *reinterpret_cast<float4*>(orow + 4) = oB;
    }
}

// ---------- fallback (atomic scatter) if ws too small ----------
__global__ void gcn_scatter(const float* __restrict__ feat, const int* __restrict__ src,
                            const int* __restrict__ dst, float* __restrict__ out,
                            float* __restrict__ deg, int n_edges) {
    long long gtid = (long long)blockIdx.x * blockDim.x + threadIdx.x;
    int edge = (int)(gtid >> 6);
    int lane = threadIdx.x & 63;
    if (edge >= n_edges) return;
    atomicAdd(&out[(long long)dst[edge] * D + lane],
              feat[(long long)src[edge] * D + lane]);
    if (lane == 0) atomicAdd(&deg[dst[edge]], 1.0f);
}
__global__ void gcn_finalize(float* __restrict__ out, const float* __restrict__ deg,
                             int total) {
    int i = blockIdx.x * blockDim.x + threadIdx.x;
    if (i >= total) return;
    float dg = deg[i >> 6];
    out[i] = (dg > 0.0f) ? out[i] / dg : 0.0f;
}

extern "C" void kernel_launch(void* const* d_in, const int* in_sizes, int n_in,
                              void* d_out, int out_size, void* d_ws, size_t ws_size,
                              hipStream_t stream) {
    const float* feat = (const float*)d_in[0];
    const int* src = (const int*)d_in[1];
    const int* dst = (const int*)d_in[2];
    float* out = (float*)d_out;
    int n_edges = in_sizes[1];

    int nchunk = (n_edges + CHUNK - 1) / CHUNK;
    size_t ncounts = (size_t)NB * nchunk;
    size_t f16_bytes = (size_t)N_NODES * D * sizeof(_Float16);   // 12.8 MB
    size_t need = f16_bytes + (ncounts + NB + NB + 1) * sizeof(int)
                + (size_t)n_edges * 2 * sizeof(unsigned);

    if (ws_size < need) {
        float* deg = (float*)d_ws;
        int total = N_NODES * D;
        hipMemsetAsync(out, 0, (size_t)total * sizeof(float), stream);
        hipMemsetAsync(deg, 0, (size_t)N_NODES * sizeof(float), stream);
        long long threads = (long long)n_edges * 64;
        int grid = (int)((threads + 255) / 256);
        gcn_scatter<<<grid, 256, 0, stream>>>(feat, src, dst, out, deg, n_edges);
        gcn_finalize<<<(total + 255) / 256, 256, 0, stream>>>(out, deg, total);
        return;
    }

    char* wp = (char*)d_ws;
    _Float16* feat16 = (_Float16*)wp;            wp += f16_bytes;
    int* counts = (int*)wp;                      wp += ncounts * sizeof(int);
    int* totals = (int*)wp;                      wp += (size_t)NB * sizeof(int);
    int* base = (int*)wp;                        wp += (size_t)(NB + 1) * sizeof(int);
    unsigned* sorted = (unsigned*)wp;            wp += (size_t)n_edges * sizeof(unsigned);
    unsigned* sorted2 = (unsigned*)wp;           // spill path only

    int n4pairs = N_NODES * D / 8;               // 800K half8 rows-worth
    int chgrid = (nchunk > 256) ? nchunk : 256;
    convhist<<<chgrid, 1024, 0, stream>>>((const float4*)feat, (float4*)feat16,
                                          n4pairs, dst, counts, nchunk, n_edges);
    scanB<<<NB, 256, 0, stream>>>(counts, totals, nchunk);
    baseK<<<1, 1024, 0, stream>>>(totals, base, n_edges);
    scatter2<<<nchunk, 1024, 0, stream>>>(src, dst, counts, base, sorted,
                                          nchunk, n_edges);
    sortGather<<<NB, 1024, 0, stream>>>(feat16, sorted, base, sorted2, out);
}